// Round 1
// baseline (1177.316 us; speedup 1.0000x reference)
//
#include <hip/hip_runtime.h>
#include <math.h>

#define DIM   96
#define C4    384
#define STYLE 128
#define LAT   8
#define KK    7
#define BB    2
#define SPD   48
#define SP3   (SPD*SPD*SPD)   /* 110592 */
#define EPSV  1e-6f

/* ---- kconv tile geometry (R8: register y-blocking) ----
   Each thread: 3(y) x 8(x) outputs. Block 192 = 6(tx) x 4(ty) x 8(tz).
   Tile: 8z x 12y x 48x. Halo: 14 x 18 x 54.
   XTS=60 (row stride, floats): ≡4 mod 8 -> b128 lane bases spread over the
   8 possible (mod-4-aligned) bank classes; ≡0 mod 4 keeps 16B alignment.
   YROWP=19 (padded rows per z-plane): 28*19 ≡ 20, 28*3 ≡ 20 (mod 32), so
   tz (plane step), ty (3-row step) and tx (8-float step) jointly cover all
   8 bank classes. An even row count (18) would collapse ty/tz to 4 classes
   (the old 4.0e8-conflict regime). */
#define XTS   60
#define YB    3
#define YSPAN 12              /* 4*YB */
#define ZSPAN 8
#define YROWS 18              /* YSPAN+6 staged rows */
#define YROWP 19              /* padded row stride per z-plane */
#define ZPL   14              /* ZSPAN+6 planes */

/* workspace layout in floats */
#define WS_Z    0                               /* 48: [which3][b2][l8] */
#define WS_WDW  64                              /* 2*96*343 = 65856, [b][c][k] fp32 */
#define WS_BDW  (WS_WDW + BB*DIM*343)           /* 192, [b][c] fp32 */
#define WS_W1   (WS_BDW + BB*DIM)               /* region holds W1b bf16 [b][384][96] */
#define WS_B1   (WS_W1 + BB*C4*DIM)             /* 768 fp32, [b][o4] */
#define WS_W2T  (WS_B1 + BB*C4)                 /* region holds W2b bf16 [b][96][384] */
#define WS_B2   (WS_W2T + BB*C4*DIM)            /* 192 fp32, [b][o] */
#define WS_H    (WS_B2 + BB*DIM)                /* 2*96*110592 fp32, [b][c][sp] */

typedef __attribute__((ext_vector_type(8))) __bf16 bf16x8;
typedef __attribute__((ext_vector_type(4))) __bf16 bf16x4;
typedef __attribute__((ext_vector_type(4))) float  f32x4;

/* ---------- kernel 1: style -> latent z for the three hyper nets ---------- */
__global__ __launch_bounds__(64) void kz(const float* __restrict__ s,
                                         const float* __restrict__ dwfw, const float* __restrict__ dwfb,
                                         const float* __restrict__ p1fw, const float* __restrict__ p1fb,
                                         const float* __restrict__ p2fw, const float* __restrict__ p2fb,
                                         float* __restrict__ ws) {
    int t = threadIdx.x;
    if (t >= 48) return;
    int which = t >> 4;      /* 0=dw, 1=pw1, 2=pw2 */
    int b = (t >> 3) & 1;
    int l = t & 7;
    const float* fw = (which == 0) ? dwfw : (which == 1) ? p1fw : p2fw;
    const float* fb = (which == 0) ? dwfb : (which == 1) ? p1fb : p2fb;
    float acc = fb[l];
    for (int k = 0; k < STYLE; ++k) acc += s[b*STYLE + k] * fw[l*STYLE + k];
    ws[WS_Z + which*16 + b*8 + l] = acc;
}

/* ---------- kernel 2: latent z -> per-batch conv weights/biases ---------- */
__global__ __launch_bounds__(256) void kw(const float* __restrict__ dwb,  const float* __restrict__ dwbb,
                                          const float* __restrict__ p1b,  const float* __restrict__ p1bb,
                                          const float* __restrict__ p2b,  const float* __restrict__ p2bb,
                                          float* __restrict__ ws) {
    const int n0 = BB*DIM*343;          /* w_dw  */
    const int n1 = n0 + BB*DIM;         /* b_dw  */
    const int n2 = n1 + BB*C4*DIM;      /* w1    */
    const int n3 = n2 + BB*C4;          /* b1    */
    const int n4 = n3 + BB*C4*DIM;      /* w2    */
    const int n5 = n4 + BB*DIM;         /* b2    */
    int i = blockIdx.x * blockDim.x + threadIdx.x;
    if (i >= n5) return;
    const float* zdw = ws + WS_Z;
    const float* z1  = ws + WS_Z + 16;
    const float* z2  = ws + WS_Z + 32;
    if (i < n0) {
        int b = i / (DIM*343); int r = i % (DIM*343); int c = r / 343; int k = r % 343;
        const float* bank = dwb + ((size_t)(c*343 + k))*LAT;
        const float* z = zdw + b*8;
        float a = 0.f;
        #pragma unroll
        for (int l = 0; l < LAT; ++l) a += bank[l]*z[l];
        ws[WS_WDW + i] = a;
    } else if (i < n1) {
        int j = i - n0; int b = j / DIM; int c = j % DIM;
        const float* z = zdw + b*8;
        float a = 0.f;
        #pragma unroll
        for (int l = 0; l < LAT; ++l) a += dwbb[c*LAT + l]*z[l];
        ws[WS_BDW + j] = a;
    } else if (i < n2) {
        int j = i - n1; int b = j / (C4*DIM); int r = j % (C4*DIM); int o = r / DIM; int c = r % DIM;
        const float* z = z1 + b*8;
        const float* bank = p1b + ((size_t)(o*DIM + c))*LAT;
        float a = 0.f;
        #pragma unroll
        for (int l = 0; l < LAT; ++l) a += bank[l]*z[l];
        ((__bf16*)(ws + WS_W1))[j] = (__bf16)a;          /* [b][o][c] */
    } else if (i < n3) {
        int j = i - n2; int b = j / C4; int o = j % C4;
        const float* z = z1 + b*8;
        float a = 0.f;
        #pragma unroll
        for (int l = 0; l < LAT; ++l) a += p1bb[o*LAT + l]*z[l];
        ws[WS_B1 + j] = a;
    } else if (i < n4) {
        int j = i - n3; int b = j / (C4*DIM); int r = j % (C4*DIM); int o = r / C4; int c4 = r % C4;
        const float* z = z2 + b*8;
        const float* bank = p2b + ((size_t)(o*C4 + c4))*LAT;
        float a = 0.f;
        #pragma unroll
        for (int l = 0; l < LAT; ++l) a += bank[l]*z[l];
        ((__bf16*)(ws + WS_W2T))[j] = (__bf16)a;         /* [b][o][c4] */
    } else {
        int j = i - n4; int b = j / DIM; int o = j % DIM;
        const float* z = z2 + b*8;
        float a = 0.f;
        #pragma unroll
        for (int l = 0; l < LAT; ++l) a += p2bb[o*LAT + l]*z[l];
        ws[WS_B2 + j] = a;
    }
}

/* ---------- kernel 3: depthwise 7x7x7 conv (+bias) -> h in ws ----------
   R8: register y-blocking. Each thread owns a 3(y) x 8(x) output patch and
   streams LDS rows ONCE per (dz,row), scattering each row into the (up to 3)
   y-accumulators whose dy matches. LDS row reads drop from 49*14 to 9*14
   floats per 24-output patch slice (2.33x), with identical FMA count — the
   2.05e8 SQ_LDS_BANK_CONFLICT (~330 us of stall at the measured ~1 cyc/evt)
   scales down with the read count. All r/yl/dx loops fully unrolled so
   acc/wv/rr indexing is compile-time (no scratch). LDS 65408 B -> 2 blk/CU. */
__global__ __launch_bounds__(192) void kconv(const float* __restrict__ x, float* __restrict__ ws) {
    __shared__ __align__(16) float xt[ZPL*YROWP*XTS];  /* 14*19*60*4 = 63840 B */
    __shared__ __align__(16) float wl[49*8];           /*  1568 B */
    int tid = threadIdx.x;
    int zt = blockIdx.x >> 2, yt = blockIdx.x & 3;     /* 6 z-tiles x 4 y-tiles */
    int c = blockIdx.y, b = blockIdx.z;
    int z0 = zt*ZSPAN, y0 = yt*YSPAN;

    const float* wsrc = ws + WS_WDW + ((size_t)(b*DIM + c))*343;
    for (int i = tid; i < 49*8; i += 192) {
        int r = i >> 3, dx = i & 7;
        wl[i] = (dx < 7) ? wsrc[r*7 + dx] : 0.f;
    }
    const float* xsrc = x + ((size_t)(b*DIM + c))*SP3;
    for (int i = tid; i < ZPL*YROWS*54; i += 192) {    /* 13608 elems */
        int iz = i / (YROWS*54); int r = i % (YROWS*54); int iy = r / 54; int ix = r % 54;
        int gz = z0 - 3 + iz, gy = y0 - 3 + iy, gx = ix - 3;
        float v = 0.f;
        if ((unsigned)gz < 48u && (unsigned)gy < 48u && (unsigned)gx < 48u)
            v = xsrc[(gz*SPD + gy)*SPD + gx];
        xt[(iz*YROWP + iy)*XTS + ix] = v;
    }
    __syncthreads();

    int tx = tid % 6; int ty = (tid/6) & 3; int tz = tid / 24;
    int xb = tx*8;
    float acc[YB][8];
    #pragma unroll
    for (int yl = 0; yl < YB; ++yl)
        #pragma unroll
        for (int j = 0; j < 8; ++j) acc[yl][j] = 0.f;

    #pragma unroll 1
    for (int dz = 0; dz < 7; ++dz) {
        /* preload this dz's 49 weights into registers (uniform LDS reads) */
        float wv[7][7];
        #pragma unroll
        for (int dy = 0; dy < 7; ++dy) {
            const float* wr = &wl[(dz*7 + dy)*8];
            float4 w0 = *(const float4*)(wr);
            float4 w1 = *(const float4*)(wr + 4);
            wv[dy][0]=w0.x; wv[dy][1]=w0.y; wv[dy][2]=w0.z; wv[dy][3]=w0.w;
            wv[dy][4]=w1.x; wv[dy][5]=w1.y; wv[dy][6]=w1.z;
        }
        const int zr = (tz + dz)*YROWP + ty*YB;
        #pragma unroll
        for (int r = 0; r < YB + 6; ++r) {
            const float* row = &xt[(zr + r)*XTS + xb];
            float4 r0 = *(const float4*)(row);
            float4 r1 = *(const float4*)(row + 4);
            float4 r2 = *(const float4*)(row + 8);
            float2 r3 = *(const float2*)(row + 12);
            float rr[14] = {r0.x,r0.y,r0.z,r0.w, r1.x,r1.y,r1.z,r1.w,
                            r2.x,r2.y,r2.z,r2.w, r3.x,r3.y};
            #pragma unroll
            for (int yl = 0; yl < YB; ++yl) {
                const int dy = r - yl;
                if (dy >= 0 && dy < 7) {
                    #pragma unroll
                    for (int dx = 0; dx < 7; ++dx)
                        #pragma unroll
                        for (int j = 0; j < 8; ++j)
                            acc[yl][j] += wv[dy][dx]*rr[dx+j];
                }
            }
        }
    }

    float bias = ws[WS_BDW + b*DIM + c];
    #pragma unroll
    for (int yl = 0; yl < YB; ++yl) {
        float* hdst = ws + WS_H + ((size_t)(b*DIM + c))*SP3
                    + (((z0+tz)*SPD + (y0 + ty*YB + yl))*SPD + xb);
        #pragma unroll
        for (int j = 0; j < 8; ++j) hdst[j] = acc[yl][j] + bias;
    }
}

/* ---------- kernel 4: LN + pw1 + GELU + pw2 + residual, MFMA version ---- */
__global__ __launch_bounds__(256) void kpw(const float* __restrict__ x,
                                           const float* __restrict__ lnw, const float* __restrict__ lnb,
                                           const float* __restrict__ gamma,
                                           float* __restrict__ out, const float* __restrict__ ws) {
    __shared__ __align__(16) __bf16 Hn[64][104];   /* 13312 B */
    __shared__ __align__(16) __bf16 G[64][392];    /* 50176 B */
    __shared__ float2 redbuf[256];                 /*  2048 B */

    const int tid  = threadIdx.x;
    const int lane = tid & 63;
    const int w    = tid >> 6;          /* wave id: Phase-A channel quarter, GEMM N-tile */
    const int b    = blockIdx.y;
    const int sp0  = blockIdx.x * 64;

    /* ---- Phase A: load h, LayerNorm, write bf16 Hn ---- */
    {
        const float* hp = ws + WS_H + (size_t)b*DIM*SP3 + (size_t)(w*24)*SP3 + sp0 + lane;
        float hv[24]; float s = 0.f, q = 0.f;
        #pragma unroll
        for (int i = 0; i < 24; ++i) {
            float v = hp[(size_t)i*SP3];
            hv[i] = v; s += v; q += v*v;
        }
        redbuf[w*64 + lane] = make_float2(s, q);
        __syncthreads();
        float2 r0 = redbuf[lane], r1 = redbuf[64+lane], r2 = redbuf[128+lane], r3 = redbuf[192+lane];
        float st = (r0.x+r1.x) + (r2.x+r3.x);
        float qt = (r0.y+r1.y) + (r2.y+r3.y);
        float mean = st * (1.f/96.f);
        float var  = qt * (1.f/96.f) - mean*mean;
        float rstd = rsqrtf(fmaxf(var, 0.f) + EPSV);
        #pragma unroll
        for (int i = 0; i < 24; ++i) {
            float nv = (hv[i] - mean)*rstd*lnw[w*24+i] + lnb[w*24+i];
            Hn[lane][w*24 + i] = (__bf16)nv;
        }
    }
    __syncthreads();

    const __bf16* W1b = (const __bf16*)(ws + WS_W1)  + (size_t)b*C4*DIM;
    const __bf16* W2b = (const __bf16*)(ws + WS_W2T) + (size_t)b*DIM*C4;
    const float*  b1  = ws + WS_B1 + b*C4;
    const float*  b2  = ws + WS_B2 + b*DIM;

    const int l16  = lane & 15;
    const int quad = lane >> 4;

    /* ---- GEMM1: G[n][o] = gelu(W1 @ Hn + b1), N-tile w ---- */
    {
        const __bf16* bp = &Hn[w*16 + l16][quad*8];
        bf16x8 Bf0 = *(const bf16x8*)(bp);
        bf16x8 Bf1 = *(const bf16x8*)(bp + 32);
        bf16x8 Bf2 = *(const bf16x8*)(bp + 64);

        const __bf16* Arow = W1b + (size_t)l16*DIM + quad*8;
        #pragma unroll 1
        for (int mt = 0; mt < 24; ++mt) {
            const __bf16* ap = Arow + (size_t)mt*16*DIM;
            bf16x8 a0 = *(const bf16x8*)(ap);
            bf16x8 a1 = *(const bf16x8*)(ap + 32);
            bf16x8 a2 = *(const bf16x8*)(ap + 64);
            f32x4 acc = {0.f, 0.f, 0.f, 0.f};
            acc = __builtin_amdgcn_mfma_f32_16x16x32_bf16(a0, Bf0, acc, 0, 0, 0);
            acc = __builtin_amdgcn_mfma_f32_16x16x32_bf16(a1, Bf1, acc, 0, 0, 0);
            acc = __builtin_amdgcn_mfma_f32_16x16x32_bf16(a2, Bf2, acc, 0, 0, 0);
            int obase = mt*16 + quad*4;
            bf16x4 gv;
            #pragma unroll
            for (int r = 0; r < 4; ++r) {
                float t = acc[r] + b1[obase + r];
                float g = 0.5f*t*(1.f + erff(t*0.70710678f));
                gv[r] = (__bf16)g;
            }
            *(bf16x4*)&G[w*16 + l16][obase] = gv;
        }
    }
    __syncthreads();   /* enforce G write->read ordering */

    /* ---- GEMM2: out = x + gamma*(W2 @ G + b2), N-tile w ---- */
    {
        bf16x8 Bg[12];
        const __bf16* gbp = &G[w*16 + l16][quad*8];
        #pragma unroll
        for (int ks = 0; ks < 12; ++ks)
            Bg[ks] = *(const bf16x8*)(gbp + ks*32);

        const __bf16* A2row = W2b + (size_t)l16*C4 + quad*8;
        const int j = w*16 + l16;
        const size_t base = (size_t)b*DIM*SP3 + sp0 + j;
        #pragma unroll 1
        for (int mt = 0; mt < 6; ++mt) {
            const __bf16* ap = A2row + (size_t)mt*16*C4;
            f32x4 acc = {0.f, 0.f, 0.f, 0.f};
            #pragma unroll
            for (int ks = 0; ks < 12; ++ks) {
                bf16x8 a = *(const bf16x8*)(ap + ks*32);
                acc = __builtin_amdgcn_mfma_f32_16x16x32_bf16(a, Bg[ks], acc, 0, 0, 0);
            }
            int obase = mt*16 + quad*4;
            #pragma unroll
            for (int r = 0; r < 4; ++r) {
                int o = obase + r;
                size_t idx = base + (size_t)o*SP3;
                float y = acc[r] + b2[o];
                out[idx] = x[idx] + gamma[o]*y;
            }
        }
    }
}

extern "C" void kernel_launch(void* const* d_in, const int* in_sizes, int n_in,
                              void* d_out, int out_size, void* d_ws, size_t ws_size,
                              hipStream_t stream) {
    const float* x      = (const float*)d_in[0];
    const float* s      = (const float*)d_in[1];
    const float* lnw    = (const float*)d_in[2];
    const float* lnb    = (const float*)d_in[3];
    const float* gamma  = (const float*)d_in[4];
    const float* dwfw   = (const float*)d_in[5];
    const float* dwfb   = (const float*)d_in[6];
    const float* dwbank = (const float*)d_in[7];
    const float* dwbb   = (const float*)d_in[8];
    const float* p1fw   = (const float*)d_in[9];
    const float* p1fb   = (const float*)d_in[10];
    const float* p1bank = (const float*)d_in[11];
    const float* p1bb   = (const float*)d_in[12];
    const float* p2fw   = (const float*)d_in[13];
    const float* p2fb   = (const float*)d_in[14];
    const float* p2bank = (const float*)d_in[15];
    const float* p2bb   = (const float*)d_in[16];
    float* ws  = (float*)d_ws;
    float* out = (float*)d_out;

    kz<<<1, 64, 0, stream>>>(s, dwfw, dwfb, p1fw, p1fb, p2fw, p2fb, ws);
    const int totW = BB*DIM*343 + BB*DIM + BB*C4*DIM + BB*C4 + BB*C4*DIM + BB*DIM;
    kw<<<(totW + 255)/256, 256, 0, stream>>>(dwbank, dwbb, p1bank, p1bb, p2bank, p2bb, ws);
    kconv<<<dim3(24, DIM, BB), 192, 0, stream>>>(x, ws);
    kpw<<<dim3(SP3/64, BB), 256, 0, stream>>>(x, lnw, lnb, gamma, out, ws);
}

// Round 3
// 919.361 us; speedup vs baseline: 1.2806x; 1.2806x over previous
//
#include <hip/hip_runtime.h>
#include <math.h>

#define DIM   96
#define C4    384
#define STYLE 128
#define LAT   8
#define KK    7
#define BB    2
#define SPD   48
#define SP3   (SPD*SPD*SPD)   /* 110592 */
#define EPSV  1e-6f

/* ---- kconv tile geometry (R9, resubmit after infra failure) ----
   R8 post-mortem: conflicts dropped as predicted (2.05e8->8.1e7) but LDS
   65 KiB -> 1 block/CU (Occupancy 8.8%) -> latency-bound regression.
   Per-op conflict math: lane-varying addr terms tz*(YROWP*XTS) +
   ty*(YB*XTS) + tx*8 are all ≡0 mod 4 for even XTS -> b128 bases occupy
   only the 8 mod-4 bank classes -> ~8 lanes/class -> ~3x serialization on
   EVERY b128 op (measured ~23-25 extra cyc/op in both R7 and R8). Fix:
   (1) tile 8z x 8y x 48x, YB=2 -> LDS 52.8 KB -> 3 blocks/CU (9 waves);
   (2) ODD strides XTS=61, YROWP=15 + scalar b32 (ds_read2_b32) inner
   reads: tz term = 915 (odd) -> wave lanes spread over all 32 banks,
   max 4 lanes/bank (~free per m136) instead of 8x8. */
#define XTS   61              /* odd: odd plane stride => full 32-bank spread */
#define YB    2
#define YSPAN 8               /* 4*YB */
#define ZSPAN 8
#define YROWS 14              /* YSPAN+6 staged rows */
#define YROWP 15              /* odd padded row stride per z-plane */
#define ZPL   14              /* ZSPAN+6 planes */

/* workspace layout in floats */
#define WS_Z    0                               /* 48: [which3][b2][l8] */
#define WS_WDW  64                              /* 2*96*343 = 65856, [b][c][k] fp32 */
#define WS_BDW  (WS_WDW + BB*DIM*343)           /* 192, [b][c] fp32 */
#define WS_W1   (WS_BDW + BB*DIM)               /* region holds W1b bf16 [b][384][96] */
#define WS_B1   (WS_W1 + BB*C4*DIM)             /* 768 fp32, [b][o4] */
#define WS_W2T  (WS_B1 + BB*C4)                 /* region holds W2b bf16 [b][96][384] */
#define WS_B2   (WS_W2T + BB*C4*DIM)            /* 192 fp32, [b][o] */
#define WS_H    (WS_B2 + BB*DIM)                /* 2*96*110592 fp32, [b][c][sp] */

typedef __attribute__((ext_vector_type(8))) __bf16 bf16x8;
typedef __attribute__((ext_vector_type(4))) __bf16 bf16x4;
typedef __attribute__((ext_vector_type(4))) float  f32x4;

/* ---------- kernel 1: style -> latent z for the three hyper nets ---------- */
__global__ __launch_bounds__(64) void kz(const float* __restrict__ s,
                                         const float* __restrict__ dwfw, const float* __restrict__ dwfb,
                                         const float* __restrict__ p1fw, const float* __restrict__ p1fb,
                                         const float* __restrict__ p2fw, const float* __restrict__ p2fb,
                                         float* __restrict__ ws) {
    int t = threadIdx.x;
    if (t >= 48) return;
    int which = t >> 4;      /* 0=dw, 1=pw1, 2=pw2 */
    int b = (t >> 3) & 1;
    int l = t & 7;
    const float* fw = (which == 0) ? dwfw : (which == 1) ? p1fw : p2fw;
    const float* fb = (which == 0) ? dwfb : (which == 1) ? p1fb : p2fb;
    float acc = fb[l];
    for (int k = 0; k < STYLE; ++k) acc += s[b*STYLE + k] * fw[l*STYLE + k];
    ws[WS_Z + which*16 + b*8 + l] = acc;
}

/* ---------- kernel 2: latent z -> per-batch conv weights/biases ---------- */
__global__ __launch_bounds__(256) void kw(const float* __restrict__ dwb,  const float* __restrict__ dwbb,
                                          const float* __restrict__ p1b,  const float* __restrict__ p1bb,
                                          const float* __restrict__ p2b,  const float* __restrict__ p2bb,
                                          float* __restrict__ ws) {
    const int n0 = BB*DIM*343;          /* w_dw  */
    const int n1 = n0 + BB*DIM;         /* b_dw  */
    const int n2 = n1 + BB*C4*DIM;      /* w1    */
    const int n3 = n2 + BB*C4;          /* b1    */
    const int n4 = n3 + BB*C4*DIM;      /* w2    */
    const int n5 = n4 + BB*DIM;         /* b2    */
    int i = blockIdx.x * blockDim.x + threadIdx.x;
    if (i >= n5) return;
    const float* zdw = ws + WS_Z;
    const float* z1  = ws + WS_Z + 16;
    const float* z2  = ws + WS_Z + 32;
    if (i < n0) {
        int b = i / (DIM*343); int r = i % (DIM*343); int c = r / 343; int k = r % 343;
        const float* bank = dwb + ((size_t)(c*343 + k))*LAT;
        const float* z = zdw + b*8;
        float a = 0.f;
        #pragma unroll
        for (int l = 0; l < LAT; ++l) a += bank[l]*z[l];
        ws[WS_WDW + i] = a;
    } else if (i < n1) {
        int j = i - n0; int b = j / DIM; int c = j % DIM;
        const float* z = zdw + b*8;
        float a = 0.f;
        #pragma unroll
        for (int l = 0; l < LAT; ++l) a += dwbb[c*LAT + l]*z[l];
        ws[WS_BDW + j] = a;
    } else if (i < n2) {
        int j = i - n1; int b = j / (C4*DIM); int r = j % (C4*DIM); int o = r / DIM; int c = r % DIM;
        const float* z = z1 + b*8;
        const float* bank = p1b + ((size_t)(o*DIM + c))*LAT;
        float a = 0.f;
        #pragma unroll
        for (int l = 0; l < LAT; ++l) a += bank[l]*z[l];
        ((__bf16*)(ws + WS_W1))[j] = (__bf16)a;          /* [b][o][c] */
    } else if (i < n3) {
        int j = i - n2; int b = j / C4; int o = j % C4;
        const float* z = z1 + b*8;
        float a = 0.f;
        #pragma unroll
        for (int l = 0; l < LAT; ++l) a += p1bb[o*LAT + l]*z[l];
        ws[WS_B1 + j] = a;
    } else if (i < n4) {
        int j = i - n3; int b = j / (C4*DIM); int r = j % (C4*DIM); int o = r / C4; int c4 = r % C4;
        const float* z = z2 + b*8;
        const float* bank = p2b + ((size_t)(o*C4 + c4))*LAT;
        float a = 0.f;
        #pragma unroll
        for (int l = 0; l < LAT; ++l) a += bank[l]*z[l];
        ((__bf16*)(ws + WS_W2T))[j] = (__bf16)a;         /* [b][o][c4] */
    } else {
        int j = i - n4; int b = j / DIM; int o = j % DIM;
        const float* z = z2 + b*8;
        float a = 0.f;
        #pragma unroll
        for (int l = 0; l < LAT; ++l) a += p2bb[o*LAT + l]*z[l];
        ws[WS_B2 + j] = a;
    }
}

/* ---------- kernel 3: depthwise 7x7x7 conv (+bias) -> h in ws ----------
   R9: 8z x 8y x 48x tile, YB=2 register y-ring, odd strides, b32 reads.
   Per thread: 2(y) x 8(x) outputs; per dz streams 8 rows once each,
   scattering into the (<=2) matching y-accumulators. Inner reads are
   scalar floats (compiler emits ds_read2_b32 pairs): with XTS=61/YROWP=15
   the per-lane bank residue (19*tz + 26*ty + 8*tx mod 32) covers all 32
   banks, max ~4 lanes/bank -> near-conflict-free, vs the structural
   8-class/8-way ceiling of any 16B-aligned b128 scheme.
   LDS 14*15*61*4 + 1568 = 52808 B -> 3 blocks/CU (9 waves). */
__global__ __launch_bounds__(192) void kconv(const float* __restrict__ x, float* __restrict__ ws) {
    __shared__ float xt[ZPL*YROWP*XTS];                /* 14*15*61*4 = 51240 B */
    __shared__ __align__(16) float wl[49*8];           /*  1568 B */
    int tid = threadIdx.x;
    int zt = blockIdx.x / 6, yt = blockIdx.x % 6;      /* 6 z-tiles x 6 y-tiles */
    int c = blockIdx.y, b = blockIdx.z;
    int z0 = zt*ZSPAN, y0 = yt*YSPAN;

    const float* wsrc = ws + WS_WDW + ((size_t)(b*DIM + c))*343;
    for (int i = tid; i < 49*8; i += 192) {
        int r = i >> 3, dx = i & 7;
        wl[i] = (dx < 7) ? wsrc[r*7 + dx] : 0.f;
    }
    const float* xsrc = x + ((size_t)(b*DIM + c))*SP3;
    for (int i = tid; i < ZPL*YROWS*54; i += 192) {    /* 10584 elems */
        int iz = i / (YROWS*54); int r = i % (YROWS*54); int iy = r / 54; int ix = r % 54;
        int gz = z0 - 3 + iz, gy = y0 - 3 + iy, gx = ix - 3;
        float v = 0.f;
        if ((unsigned)gz < 48u && (unsigned)gy < 48u && (unsigned)gx < 48u)
            v = xsrc[(gz*SPD + gy)*SPD + gx];
        xt[(iz*YROWP + iy)*XTS + ix] = v;
    }
    __syncthreads();

    int tx = tid % 6; int ty = (tid/6) & 3; int tz = tid / 24;
    int xb = tx*8;
    float acc[YB][8];
    #pragma unroll
    for (int yl = 0; yl < YB; ++yl)
        #pragma unroll
        for (int j = 0; j < 8; ++j) acc[yl][j] = 0.f;

    #pragma unroll 1
    for (int dz = 0; dz < 7; ++dz) {
        /* preload this dz's 49 weights into registers (uniform LDS reads) */
        float wv[7][7];
        #pragma unroll
        for (int dy = 0; dy < 7; ++dy) {
            const float* wr = &wl[(dz*7 + dy)*8];
            float4 w0 = *(const float4*)(wr);
            float4 w1 = *(const float4*)(wr + 4);
            wv[dy][0]=w0.x; wv[dy][1]=w0.y; wv[dy][2]=w0.z; wv[dy][3]=w0.w;
            wv[dy][4]=w1.x; wv[dy][5]=w1.y; wv[dy][6]=w1.z;
        }
        const int zr = (tz + dz)*YROWP + ty*YB;
        #pragma unroll
        for (int r = 0; r < YB + 6; ++r) {
            const float* row = &xt[(zr + r)*XTS + xb];
            float rr[14];
            #pragma unroll
            for (int k = 0; k < 14; ++k) rr[k] = row[k];   /* b32-class reads */
            #pragma unroll
            for (int yl = 0; yl < YB; ++yl) {
                const int dy = r - yl;
                if (dy >= 0 && dy < 7) {
                    #pragma unroll
                    for (int dx = 0; dx < 7; ++dx)
                        #pragma unroll
                        for (int j = 0; j < 8; ++j)
                            acc[yl][j] += wv[dy][dx]*rr[dx+j];
                }
            }
        }
    }

    float bias = ws[WS_BDW + b*DIM + c];
    #pragma unroll
    for (int yl = 0; yl < YB; ++yl) {
        float* hdst = ws + WS_H + ((size_t)(b*DIM + c))*SP3
                    + (((z0+tz)*SPD + (y0 + ty*YB + yl))*SPD + xb);
        #pragma unroll
        for (int j = 0; j < 8; ++j) hdst[j] = acc[yl][j] + bias;
    }
}

/* ---------- kernel 4: LN + pw1 + GELU + pw2 + residual, MFMA version ---- */
__global__ __launch_bounds__(256) void kpw(const float* __restrict__ x,
                                           const float* __restrict__ lnw, const float* __restrict__ lnb,
                                           const float* __restrict__ gamma,
                                           float* __restrict__ out, const float* __restrict__ ws) {
    __shared__ __align__(16) __bf16 Hn[64][104];   /* 13312 B */
    __shared__ __align__(16) __bf16 G[64][392];    /* 50176 B */
    __shared__ float2 redbuf[256];                 /*  2048 B */

    const int tid  = threadIdx.x;
    const int lane = tid & 63;
    const int w    = tid >> 6;          /* wave id: Phase-A channel quarter, GEMM N-tile */
    const int b    = blockIdx.y;
    const int sp0  = blockIdx.x * 64;

    /* ---- Phase A: load h, LayerNorm, write bf16 Hn ---- */
    {
        const float* hp = ws + WS_H + (size_t)b*DIM*SP3 + (size_t)(w*24)*SP3 + sp0 + lane;
        float hv[24]; float s = 0.f, q = 0.f;
        #pragma unroll
        for (int i = 0; i < 24; ++i) {
            float v = hp[(size_t)i*SP3];
            hv[i] = v; s += v; q += v*v;
        }
        redbuf[w*64 + lane] = make_float2(s, q);
        __syncthreads();
        float2 r0 = redbuf[lane], r1 = redbuf[64+lane], r2 = redbuf[128+lane], r3 = redbuf[192+lane];
        float st = (r0.x+r1.x) + (r2.x+r3.x);
        float qt = (r0.y+r1.y) + (r2.y+r3.y);
        float mean = st * (1.f/96.f);
        float var  = qt * (1.f/96.f) - mean*mean;
        float rstd = rsqrtf(fmaxf(var, 0.f) + EPSV);
        #pragma unroll
        for (int i = 0; i < 24; ++i) {
            float nv = (hv[i] - mean)*rstd*lnw[w*24+i] + lnb[w*24+i];
            Hn[lane][w*24 + i] = (__bf16)nv;
        }
    }
    __syncthreads();

    const __bf16* W1b = (const __bf16*)(ws + WS_W1)  + (size_t)b*C4*DIM;
    const __bf16* W2b = (const __bf16*)(ws + WS_W2T) + (size_t)b*DIM*C4;
    const float*  b1  = ws + WS_B1 + b*C4;
    const float*  b2  = ws + WS_B2 + b*DIM;

    const int l16  = lane & 15;
    const int quad = lane >> 4;

    /* ---- GEMM1: G[n][o] = gelu(W1 @ Hn + b1), N-tile w ---- */
    {
        const __bf16* bp = &Hn[w*16 + l16][quad*8];
        bf16x8 Bf0 = *(const bf16x8*)(bp);
        bf16x8 Bf1 = *(const bf16x8*)(bp + 32);
        bf16x8 Bf2 = *(const bf16x8*)(bp + 64);

        const __bf16* Arow = W1b + (size_t)l16*DIM + quad*8;
        #pragma unroll 1
        for (int mt = 0; mt < 24; ++mt) {
            const __bf16* ap = Arow + (size_t)mt*16*DIM;
            bf16x8 a0 = *(const bf16x8*)(ap);
            bf16x8 a1 = *(const bf16x8*)(ap + 32);
            bf16x8 a2 = *(const bf16x8*)(ap + 64);
            f32x4 acc = {0.f, 0.f, 0.f, 0.f};
            acc = __builtin_amdgcn_mfma_f32_16x16x32_bf16(a0, Bf0, acc, 0, 0, 0);
            acc = __builtin_amdgcn_mfma_f32_16x16x32_bf16(a1, Bf1, acc, 0, 0, 0);
            acc = __builtin_amdgcn_mfma_f32_16x16x32_bf16(a2, Bf2, acc, 0, 0, 0);
            int obase = mt*16 + quad*4;
            bf16x4 gv;
            #pragma unroll
            for (int r = 0; r < 4; ++r) {
                float t = acc[r] + b1[obase + r];
                float g = 0.5f*t*(1.f + erff(t*0.70710678f));
                gv[r] = (__bf16)g;
            }
            *(bf16x4*)&G[w*16 + l16][obase] = gv;
        }
    }
    __syncthreads();   /* enforce G write->read ordering */

    /* ---- GEMM2: out = x + gamma*(W2 @ G + b2), N-tile w ---- */
    {
        bf16x8 Bg[12];
        const __bf16* gbp = &G[w*16 + l16][quad*8];
        #pragma unroll
        for (int ks = 0; ks < 12; ++ks)
            Bg[ks] = *(const bf16x8*)(gbp + ks*32);

        const __bf16* A2row = W2b + (size_t)l16*C4 + quad*8;
        const int j = w*16 + l16;
        const size_t base = (size_t)b*DIM*SP3 + sp0 + j;
        #pragma unroll 1
        for (int mt = 0; mt < 6; ++mt) {
            const __bf16* ap = A2row + (size_t)mt*16*C4;
            f32x4 acc = {0.f, 0.f, 0.f, 0.f};
            #pragma unroll
            for (int ks = 0; ks < 12; ++ks) {
                bf16x8 a = *(const bf16x8*)(ap + ks*32);
                acc = __builtin_amdgcn_mfma_f32_16x16x32_bf16(a, Bg[ks], acc, 0, 0, 0);
            }
            int obase = mt*16 + quad*4;
            #pragma unroll
            for (int r = 0; r < 4; ++r) {
                int o = obase + r;
                size_t idx = base + (size_t)o*SP3;
                float y = acc[r] + b2[o];
                out[idx] = x[idx] + gamma[o]*y;
            }
        }
    }
}

extern "C" void kernel_launch(void* const* d_in, const int* in_sizes, int n_in,
                              void* d_out, int out_size, void* d_ws, size_t ws_size,
                              hipStream_t stream) {
    const float* x      = (const float*)d_in[0];
    const float* s      = (const float*)d_in[1];
    const float* lnw    = (const float*)d_in[2];
    const float* lnb    = (const float*)d_in[3];
    const float* gamma  = (const float*)d_in[4];
    const float* dwfw   = (const float*)d_in[5];
    const float* dwfb   = (const float*)d_in[6];
    const float* dwbank = (const float*)d_in[7];
    const float* dwbb   = (const float*)d_in[8];
    const float* p1fw   = (const float*)d_in[9];
    const float* p1fb   = (const float*)d_in[10];
    const float* p1bank = (const float*)d_in[11];
    const float* p1bb   = (const float*)d_in[12];
    const float* p2fw   = (const float*)d_in[13];
    const float* p2fb   = (const float*)d_in[14];
    const float* p2bank = (const float*)d_in[15];
    const float* p2bb   = (const float*)d_in[16];
    float* ws  = (float*)d_ws;
    float* out = (float*)d_out;

    kz<<<1, 64, 0, stream>>>(s, dwfw, dwfb, p1fw, p1fb, p2fw, p2fb, ws);
    const int totW = BB*DIM*343 + BB*DIM + BB*C4*DIM + BB*C4 + BB*C4*DIM + BB*DIM;
    kw<<<(totW + 255)/256, 256, 0, stream>>>(dwbank, dwbb, p1bank, p1bb, p2bank, p2bb, ws);
    kconv<<<dim3(36, DIM, BB), 192, 0, stream>>>(x, ws);
    kpw<<<dim3(SP3/64, BB), 256, 0, stream>>>(x, lnw, lnb, gamma, out, ws);
}

// Round 4
// 897.318 us; speedup vs baseline: 1.3120x; 1.0246x over previous
//
#include <hip/hip_runtime.h>
#include <math.h>

#define DIM   96
#define C4    384
#define STYLE 128
#define LAT   8
#define KK    7
#define BB    2
#define SPD   48
#define SP3   (SPD*SPD*SPD)   /* 110592 */
#define EPSV  1e-6f

/* ---- kconv tile geometry (R10) ----
   R9 post-mortem: conflicts fixed (4.25e7, ~69 us) but Occupancy 17%
   (~1.5 waves/SIMD) left ds_read->FMA latency exposed: 516 us vs ~200 us
   overlapped floor. Fix: fit 4 blocks/CU (<=40960 B LDS/block).
   Tile 8z x 16y x 24x: xt = 14*23*31*4 = 39928 B, nothing else in LDS
   (weights read straight from global ws — blockIdx-uniform address ->
   scalarized broadcast loads, L2-resident, reused 112 FMA each).
   Strides stay odd (31; plane 23*31=713 ≡ 9 mod 32) -> all-32-bank
   spread verified in R9 preserved. Per-thread compute structure (YB=2
   ring, b32-class reads) identical to R9. */
#define XTS   31              /* odd row stride */
#define YB    2
#define YSPAN 16              /* 8 ty * YB */
#define ZSPAN 8
#define XSPAN 24              /* 3 tx * 8 */
#define YROWS 22              /* YSPAN+6 staged rows */
#define YROWP 23              /* odd padded row stride per z-plane */
#define ZPL   14              /* ZSPAN+6 planes */

/* workspace layout in floats */
#define WS_Z    0                               /* 48: [which3][b2][l8] */
#define WS_WDW  64                              /* 2*96*343 = 65856, [b][c][k] fp32 */
#define WS_BDW  (WS_WDW + BB*DIM*343)           /* 192, [b][c] fp32 */
#define WS_W1   (WS_BDW + BB*DIM)               /* region holds W1b bf16 [b][384][96] */
#define WS_B1   (WS_W1 + BB*C4*DIM)             /* 768 fp32, [b][o4] */
#define WS_W2T  (WS_B1 + BB*C4)                 /* region holds W2b bf16 [b][96][384] */
#define WS_B2   (WS_W2T + BB*C4*DIM)            /* 192 fp32, [b][o] */
#define WS_H    (WS_B2 + BB*DIM)                /* 2*96*110592 fp32, [b][c][sp] */

typedef __attribute__((ext_vector_type(8))) __bf16 bf16x8;
typedef __attribute__((ext_vector_type(4))) __bf16 bf16x4;
typedef __attribute__((ext_vector_type(4))) float  f32x4;

/* ---------- kernel 1: style -> latent z for the three hyper nets ---------- */
__global__ __launch_bounds__(64) void kz(const float* __restrict__ s,
                                         const float* __restrict__ dwfw, const float* __restrict__ dwfb,
                                         const float* __restrict__ p1fw, const float* __restrict__ p1fb,
                                         const float* __restrict__ p2fw, const float* __restrict__ p2fb,
                                         float* __restrict__ ws) {
    int t = threadIdx.x;
    if (t >= 48) return;
    int which = t >> 4;      /* 0=dw, 1=pw1, 2=pw2 */
    int b = (t >> 3) & 1;
    int l = t & 7;
    const float* fw = (which == 0) ? dwfw : (which == 1) ? p1fw : p2fw;
    const float* fb = (which == 0) ? dwfb : (which == 1) ? p1fb : p2fb;
    float acc = fb[l];
    for (int k = 0; k < STYLE; ++k) acc += s[b*STYLE + k] * fw[l*STYLE + k];
    ws[WS_Z + which*16 + b*8 + l] = acc;
}

/* ---------- kernel 2: latent z -> per-batch conv weights/biases ---------- */
__global__ __launch_bounds__(256) void kw(const float* __restrict__ dwb,  const float* __restrict__ dwbb,
                                          const float* __restrict__ p1b,  const float* __restrict__ p1bb,
                                          const float* __restrict__ p2b,  const float* __restrict__ p2bb,
                                          float* __restrict__ ws) {
    const int n0 = BB*DIM*343;          /* w_dw  */
    const int n1 = n0 + BB*DIM;         /* b_dw  */
    const int n2 = n1 + BB*C4*DIM;      /* w1    */
    const int n3 = n2 + BB*C4;          /* b1    */
    const int n4 = n3 + BB*C4*DIM;      /* w2    */
    const int n5 = n4 + BB*DIM;         /* b2    */
    int i = blockIdx.x * blockDim.x + threadIdx.x;
    if (i >= n5) return;
    const float* zdw = ws + WS_Z;
    const float* z1  = ws + WS_Z + 16;
    const float* z2  = ws + WS_Z + 32;
    if (i < n0) {
        int b = i / (DIM*343); int r = i % (DIM*343); int c = r / 343; int k = r % 343;
        const float* bank = dwb + ((size_t)(c*343 + k))*LAT;
        const float* z = zdw + b*8;
        float a = 0.f;
        #pragma unroll
        for (int l = 0; l < LAT; ++l) a += bank[l]*z[l];
        ws[WS_WDW + i] = a;
    } else if (i < n1) {
        int j = i - n0; int b = j / DIM; int c = j % DIM;
        const float* z = zdw + b*8;
        float a = 0.f;
        #pragma unroll
        for (int l = 0; l < LAT; ++l) a += dwbb[c*LAT + l]*z[l];
        ws[WS_BDW + j] = a;
    } else if (i < n2) {
        int j = i - n1; int b = j / (C4*DIM); int r = j % (C4*DIM); int o = r / DIM; int c = r % DIM;
        const float* z = z1 + b*8;
        const float* bank = p1b + ((size_t)(o*DIM + c))*LAT;
        float a = 0.f;
        #pragma unroll
        for (int l = 0; l < LAT; ++l) a += bank[l]*z[l];
        ((__bf16*)(ws + WS_W1))[j] = (__bf16)a;          /* [b][o][c] */
    } else if (i < n3) {
        int j = i - n2; int b = j / C4; int o = j % C4;
        const float* z = z1 + b*8;
        float a = 0.f;
        #pragma unroll
        for (int l = 0; l < LAT; ++l) a += p1bb[o*LAT + l]*z[l];
        ws[WS_B1 + j] = a;
    } else if (i < n4) {
        int j = i - n3; int b = j / (C4*DIM); int r = j % (C4*DIM); int o = r / C4; int c4 = r % C4;
        const float* z = z2 + b*8;
        const float* bank = p2b + ((size_t)(o*C4 + c4))*LAT;
        float a = 0.f;
        #pragma unroll
        for (int l = 0; l < LAT; ++l) a += bank[l]*z[l];
        ((__bf16*)(ws + WS_W2T))[j] = (__bf16)a;         /* [b][o][c4] */
    } else {
        int j = i - n4; int b = j / DIM; int o = j % DIM;
        const float* z = z2 + b*8;
        float a = 0.f;
        #pragma unroll
        for (int l = 0; l < LAT; ++l) a += p2bb[o*LAT + l]*z[l];
        ws[WS_B2 + j] = a;
    }
}

/* ---------- kernel 3: depthwise 7x7x7 conv (+bias) -> h in ws ----------
   R10: 8z x 16y x 24x tile, YB=2 register y-ring, odd strides, b32 reads,
   weights from global (uniform/broadcast), 39928 B LDS -> 4 blocks/CU
   (12 waves, 37.5% occupancy target). */
__global__ __launch_bounds__(192) void kconv(const float* __restrict__ x, float* __restrict__ ws) {
    __shared__ float xt[ZPL*YROWP*XTS];                /* 14*23*31*4 = 39928 B */
    int tid = threadIdx.x;
    int bx = blockIdx.x;                               /* 36 = 6z * 3y * 2x */
    int zt = bx / 6;
    int rt = bx % 6; int yt = rt >> 1; int xti = rt & 1;
    int c = blockIdx.y, b = blockIdx.z;
    int z0 = zt*ZSPAN, y0 = yt*YSPAN, x0 = xti*XSPAN;

    const float* xsrc = x + ((size_t)(b*DIM + c))*SP3;
    for (int i = tid; i < ZPL*YROWS*30; i += 192) {    /* 9240 elems */
        int iz = i / (YROWS*30); int r = i % (YROWS*30); int iy = r / 30; int ix = r % 30;
        int gz = z0 - 3 + iz, gy = y0 - 3 + iy, gx = x0 + ix - 3;
        float v = 0.f;
        if ((unsigned)gz < 48u && (unsigned)gy < 48u && (unsigned)gx < 48u)
            v = xsrc[(gz*SPD + gy)*SPD + gx];
        xt[(iz*YROWP + iy)*XTS + ix] = v;
    }
    __syncthreads();

    int tz = tid / 24; int rem = tid % 24; int ty = rem / 3; int tx = rem % 3;
    int xb = tx*8;
    float acc[YB][8];
    #pragma unroll
    for (int yl = 0; yl < YB; ++yl)
        #pragma unroll
        for (int j = 0; j < 8; ++j) acc[yl][j] = 0.f;

    const float* wsrc = ws + WS_WDW + ((size_t)(b*DIM + c))*343;

    #pragma unroll 1
    for (int dz = 0; dz < 7; ++dz) {
        /* this dz's 49 weights: uniform global loads (L2-hit, broadcast) */
        float wv[7][7];
        const float* wp = wsrc + dz*49;
        #pragma unroll
        for (int dy = 0; dy < 7; ++dy)
            #pragma unroll
            for (int dx = 0; dx < 7; ++dx)
                wv[dy][dx] = wp[dy*7 + dx];

        const int zr = (tz + dz)*YROWP + ty*YB;
        #pragma unroll
        for (int r = 0; r < YB + 6; ++r) {
            const float* row = &xt[(zr + r)*XTS + xb];
            float rr[14];
            #pragma unroll
            for (int k = 0; k < 14; ++k) rr[k] = row[k];   /* b32-class reads */
            #pragma unroll
            for (int yl = 0; yl < YB; ++yl) {
                const int dy = r - yl;
                if (dy >= 0 && dy < 7) {
                    #pragma unroll
                    for (int dx = 0; dx < 7; ++dx)
                        #pragma unroll
                        for (int j = 0; j < 8; ++j)
                            acc[yl][j] += wv[dy][dx]*rr[dx+j];
                }
            }
        }
    }

    float bias = ws[WS_BDW + b*DIM + c];
    #pragma unroll
    for (int yl = 0; yl < YB; ++yl) {
        float* hdst = ws + WS_H + ((size_t)(b*DIM + c))*SP3
                    + (((z0+tz)*SPD + (y0 + ty*YB + yl))*SPD + (x0 + xb));
        #pragma unroll
        for (int j = 0; j < 8; ++j) hdst[j] = acc[yl][j] + bias;
    }
}

/* ---------- kernel 4: LN + pw1 + GELU + pw2 + residual, MFMA version ---- */
__global__ __launch_bounds__(256) void kpw(const float* __restrict__ x,
                                           const float* __restrict__ lnw, const float* __restrict__ lnb,
                                           const float* __restrict__ gamma,
                                           float* __restrict__ out, const float* __restrict__ ws) {
    __shared__ __align__(16) __bf16 Hn[64][104];   /* 13312 B */
    __shared__ __align__(16) __bf16 G[64][392];    /* 50176 B */
    __shared__ float2 redbuf[256];                 /*  2048 B */

    const int tid  = threadIdx.x;
    const int lane = tid & 63;
    const int w    = tid >> 6;          /* wave id: Phase-A channel quarter, GEMM N-tile */
    const int b    = blockIdx.y;
    const int sp0  = blockIdx.x * 64;

    /* ---- Phase A: load h, LayerNorm, write bf16 Hn ---- */
    {
        const float* hp = ws + WS_H + (size_t)b*DIM*SP3 + (size_t)(w*24)*SP3 + sp0 + lane;
        float hv[24]; float s = 0.f, q = 0.f;
        #pragma unroll
        for (int i = 0; i < 24; ++i) {
            float v = hp[(size_t)i*SP3];
            hv[i] = v; s += v; q += v*v;
        }
        redbuf[w*64 + lane] = make_float2(s, q);
        __syncthreads();
        float2 r0 = redbuf[lane], r1 = redbuf[64+lane], r2 = redbuf[128+lane], r3 = redbuf[192+lane];
        float st = (r0.x+r1.x) + (r2.x+r3.x);
        float qt = (r0.y+r1.y) + (r2.y+r3.y);
        float mean = st * (1.f/96.f);
        float var  = qt * (1.f/96.f) - mean*mean;
        float rstd = rsqrtf(fmaxf(var, 0.f) + EPSV);
        #pragma unroll
        for (int i = 0; i < 24; ++i) {
            float nv = (hv[i] - mean)*rstd*lnw[w*24+i] + lnb[w*24+i];
            Hn[lane][w*24 + i] = (__bf16)nv;
        }
    }
    __syncthreads();

    const __bf16* W1b = (const __bf16*)(ws + WS_W1)  + (size_t)b*C4*DIM;
    const __bf16* W2b = (const __bf16*)(ws + WS_W2T) + (size_t)b*DIM*C4;
    const float*  b1  = ws + WS_B1 + b*C4;
    const float*  b2  = ws + WS_B2 + b*DIM;

    const int l16  = lane & 15;
    const int quad = lane >> 4;

    /* ---- GEMM1: G[n][o] = gelu(W1 @ Hn + b1), N-tile w ---- */
    {
        const __bf16* bp = &Hn[w*16 + l16][quad*8];
        bf16x8 Bf0 = *(const bf16x8*)(bp);
        bf16x8 Bf1 = *(const bf16x8*)(bp + 32);
        bf16x8 Bf2 = *(const bf16x8*)(bp + 64);

        const __bf16* Arow = W1b + (size_t)l16*DIM + quad*8;
        #pragma unroll 1
        for (int mt = 0; mt < 24; ++mt) {
            const __bf16* ap = Arow + (size_t)mt*16*DIM;
            bf16x8 a0 = *(const bf16x8*)(ap);
            bf16x8 a1 = *(const bf16x8*)(ap + 32);
            bf16x8 a2 = *(const bf16x8*)(ap + 64);
            f32x4 acc = {0.f, 0.f, 0.f, 0.f};
            acc = __builtin_amdgcn_mfma_f32_16x16x32_bf16(a0, Bf0, acc, 0, 0, 0);
            acc = __builtin_amdgcn_mfma_f32_16x16x32_bf16(a1, Bf1, acc, 0, 0, 0);
            acc = __builtin_amdgcn_mfma_f32_16x16x32_bf16(a2, Bf2, acc, 0, 0, 0);
            int obase = mt*16 + quad*4;
            bf16x4 gv;
            #pragma unroll
            for (int r = 0; r < 4; ++r) {
                float t = acc[r] + b1[obase + r];
                float g = 0.5f*t*(1.f + erff(t*0.70710678f));
                gv[r] = (__bf16)g;
            }
            *(bf16x4*)&G[w*16 + l16][obase] = gv;
        }
    }
    __syncthreads();   /* enforce G write->read ordering */

    /* ---- GEMM2: out = x + gamma*(W2 @ G + b2), N-tile w ---- */
    {
        bf16x8 Bg[12];
        const __bf16* gbp = &G[w*16 + l16][quad*8];
        #pragma unroll
        for (int ks = 0; ks < 12; ++ks)
            Bg[ks] = *(const bf16x8*)(gbp + ks*32);

        const __bf16* A2row = W2b + (size_t)l16*C4 + quad*8;
        const int j = w*16 + l16;
        const size_t base = (size_t)b*DIM*SP3 + sp0 + j;
        #pragma unroll 1
        for (int mt = 0; mt < 6; ++mt) {
            const __bf16* ap = A2row + (size_t)mt*16*C4;
            f32x4 acc = {0.f, 0.f, 0.f, 0.f};
            #pragma unroll
            for (int ks = 0; ks < 12; ++ks) {
                bf16x8 a = *(const bf16x8*)(ap + ks*32);
                acc = __builtin_amdgcn_mfma_f32_16x16x32_bf16(a, Bg[ks], acc, 0, 0, 0);
            }
            int obase = mt*16 + quad*4;
            #pragma unroll
            for (int r = 0; r < 4; ++r) {
                int o = obase + r;
                size_t idx = base + (size_t)o*SP3;
                float y = acc[r] + b2[o];
                out[idx] = x[idx] + gamma[o]*y;
            }
        }
    }
}

extern "C" void kernel_launch(void* const* d_in, const int* in_sizes, int n_in,
                              void* d_out, int out_size, void* d_ws, size_t ws_size,
                              hipStream_t stream) {
    const float* x      = (const float*)d_in[0];
    const float* s      = (const float*)d_in[1];
    const float* lnw    = (const float*)d_in[2];
    const float* lnb    = (const float*)d_in[3];
    const float* gamma  = (const float*)d_in[4];
    const float* dwfw   = (const float*)d_in[5];
    const float* dwfb   = (const float*)d_in[6];
    const float* dwbank = (const float*)d_in[7];
    const float* dwbb   = (const float*)d_in[8];
    const float* p1fw   = (const float*)d_in[9];
    const float* p1fb   = (const float*)d_in[10];
    const float* p1bank = (const float*)d_in[11];
    const float* p1bb   = (const float*)d_in[12];
    const float* p2fw   = (const float*)d_in[13];
    const float* p2fb   = (const float*)d_in[14];
    const float* p2bank = (const float*)d_in[15];
    const float* p2bb   = (const float*)d_in[16];
    float* ws  = (float*)d_ws;
    float* out = (float*)d_out;

    kz<<<1, 64, 0, stream>>>(s, dwfw, dwfb, p1fw, p1fb, p2fw, p2fb, ws);
    const int totW = BB*DIM*343 + BB*DIM + BB*C4*DIM + BB*C4 + BB*C4*DIM + BB*DIM;
    kw<<<(totW + 255)/256, 256, 0, stream>>>(dwbank, dwbb, p1bank, p1bb, p2bank, p2bb, ws);
    kconv<<<dim3(36, DIM, BB), 192, 0, stream>>>(x, ws);
    kpw<<<dim3(SP3/64, BB), 256, 0, stream>>>(x, lnw, lnb, gamma, out, ws);
}

// Round 5
// 681.935 us; speedup vs baseline: 1.7264x; 1.3158x over previous
//
#include <hip/hip_runtime.h>
#include <math.h>

#define DIM   96
#define C4    384
#define STYLE 128
#define LAT   8
#define KK    7
#define BB    2
#define SPD   48
#define SP3   (SPD*SPD*SPD)   /* 110592 */
#define EPSV  1e-6f

/* ---- kconv tile geometry (R11: bf16 LDS tile) ----
   R10 post-mortem: LDS 39936 still gave only ~2 blocks/CU (17% occ, same
   as R9 at 53248) -> effective concurrent-WG LDS pool looks like ~110-120
   KiB, not 160. Fix: make LDS so small the cap can't bind. x-halo tile in
   BF16: 14 planes x 23 row-slots x 30 elems x 2 B = 19320 B -> 4-5+
   blocks/CU under any pool model. Row window = 14 bf16 = 7 dwords (was 14)
   -> LDS read ops halve; dword stride 15 (odd) keeps R9's verified
   all-32-bank spread, and 16B alignment is unprovable so no b128 class
   problem. Unpack = 2 VALU/dword (<<16, &0xffff0000). Numerics: 0.2% rel
   err on h -> ~4e-9 on out (gamma=1e-6 scale); GEMMs already bf16.
   Tile 8z x 16y x 24x, 192 thr = 8tz x 8ty x 3tx, YB=2 ring (structure
   verified in R9/R10). Weights stay fp32 from global (uniform s_loads). */
#define XTS_E 30              /* bf16 elems per row slot (exact, dword stride 15 odd) */
#define YB    2
#define YSPAN 16              /* 8 ty * YB */
#define ZSPAN 8
#define XSPAN 24              /* 3 tx * 8 */
#define YROWS 22              /* YSPAN+6 staged rows */
#define YROWP 23              /* row-slot stride per z-plane (plane dstride 345, odd) */
#define ZPL   14              /* ZSPAN+6 planes */

/* workspace layout in floats */
#define WS_Z    0                               /* 48: [which3][b2][l8] */
#define WS_WDW  64                              /* 2*96*343 = 65856, [b][c][k] fp32 */
#define WS_BDW  (WS_WDW + BB*DIM*343)           /* 192, [b][c] fp32 */
#define WS_W1   (WS_BDW + BB*DIM)               /* region holds W1b bf16 [b][384][96] */
#define WS_B1   (WS_W1 + BB*C4*DIM)             /* 768 fp32, [b][o4] */
#define WS_W2T  (WS_B1 + BB*C4)                 /* region holds W2b bf16 [b][96][384] */
#define WS_B2   (WS_W2T + BB*C4*DIM)            /* 192 fp32, [b][o] */
#define WS_H    (WS_B2 + BB*DIM)                /* 2*96*110592 fp32, [b][c][sp] */

typedef __attribute__((ext_vector_type(8))) __bf16 bf16x8;
typedef __attribute__((ext_vector_type(4))) __bf16 bf16x4;
typedef __attribute__((ext_vector_type(4))) float  f32x4;

/* ---------- kernel 1: style -> latent z for the three hyper nets ---------- */
__global__ __launch_bounds__(64) void kz(const float* __restrict__ s,
                                         const float* __restrict__ dwfw, const float* __restrict__ dwfb,
                                         const float* __restrict__ p1fw, const float* __restrict__ p1fb,
                                         const float* __restrict__ p2fw, const float* __restrict__ p2fb,
                                         float* __restrict__ ws) {
    int t = threadIdx.x;
    if (t >= 48) return;
    int which = t >> 4;      /* 0=dw, 1=pw1, 2=pw2 */
    int b = (t >> 3) & 1;
    int l = t & 7;
    const float* fw = (which == 0) ? dwfw : (which == 1) ? p1fw : p2fw;
    const float* fb = (which == 0) ? dwfb : (which == 1) ? p1fb : p2fb;
    float acc = fb[l];
    for (int k = 0; k < STYLE; ++k) acc += s[b*STYLE + k] * fw[l*STYLE + k];
    ws[WS_Z + which*16 + b*8 + l] = acc;
}

/* ---------- kernel 2: latent z -> per-batch conv weights/biases ---------- */
__global__ __launch_bounds__(256) void kw(const float* __restrict__ dwb,  const float* __restrict__ dwbb,
                                          const float* __restrict__ p1b,  const float* __restrict__ p1bb,
                                          const float* __restrict__ p2b,  const float* __restrict__ p2bb,
                                          float* __restrict__ ws) {
    const int n0 = BB*DIM*343;          /* w_dw  */
    const int n1 = n0 + BB*DIM;         /* b_dw  */
    const int n2 = n1 + BB*C4*DIM;      /* w1    */
    const int n3 = n2 + BB*C4;          /* b1    */
    const int n4 = n3 + BB*C4*DIM;      /* w2    */
    const int n5 = n4 + BB*DIM;         /* b2    */
    int i = blockIdx.x * blockDim.x + threadIdx.x;
    if (i >= n5) return;
    const float* zdw = ws + WS_Z;
    const float* z1  = ws + WS_Z + 16;
    const float* z2  = ws + WS_Z + 32;
    if (i < n0) {
        int b = i / (DIM*343); int r = i % (DIM*343); int c = r / 343; int k = r % 343;
        const float* bank = dwb + ((size_t)(c*343 + k))*LAT;
        const float* z = zdw + b*8;
        float a = 0.f;
        #pragma unroll
        for (int l = 0; l < LAT; ++l) a += bank[l]*z[l];
        ws[WS_WDW + i] = a;
    } else if (i < n1) {
        int j = i - n0; int b = j / DIM; int c = j % DIM;
        const float* z = zdw + b*8;
        float a = 0.f;
        #pragma unroll
        for (int l = 0; l < LAT; ++l) a += dwbb[c*LAT + l]*z[l];
        ws[WS_BDW + j] = a;
    } else if (i < n2) {
        int j = i - n1; int b = j / (C4*DIM); int r = j % (C4*DIM); int o = r / DIM; int c = r % DIM;
        const float* z = z1 + b*8;
        const float* bank = p1b + ((size_t)(o*DIM + c))*LAT;
        float a = 0.f;
        #pragma unroll
        for (int l = 0; l < LAT; ++l) a += bank[l]*z[l];
        ((__bf16*)(ws + WS_W1))[j] = (__bf16)a;          /* [b][o][c] */
    } else if (i < n3) {
        int j = i - n2; int b = j / C4; int o = j % C4;
        const float* z = z1 + b*8;
        float a = 0.f;
        #pragma unroll
        for (int l = 0; l < LAT; ++l) a += p1bb[o*LAT + l]*z[l];
        ws[WS_B1 + j] = a;
    } else if (i < n4) {
        int j = i - n3; int b = j / (C4*DIM); int r = j % (C4*DIM); int o = r / C4; int c4 = r % C4;
        const float* z = z2 + b*8;
        const float* bank = p2b + ((size_t)(o*C4 + c4))*LAT;
        float a = 0.f;
        #pragma unroll
        for (int l = 0; l < LAT; ++l) a += bank[l]*z[l];
        ((__bf16*)(ws + WS_W2T))[j] = (__bf16)a;         /* [b][o][c4] */
    } else {
        int j = i - n4; int b = j / DIM; int o = j % DIM;
        const float* z = z2 + b*8;
        float a = 0.f;
        #pragma unroll
        for (int l = 0; l < LAT; ++l) a += p2bb[o*LAT + l]*z[l];
        ws[WS_B2 + j] = a;
    }
}

/* ---------- kernel 3: depthwise 7x7x7 conv (+bias) -> h in ws ----------
   R11: bf16 LDS x-tile (19320 B), 8z x 16y x 24x, YB=2 register y-ring,
   odd dword strides, dword reads + 2-VALU unpack, weights from global
   (uniform/broadcast s_loads), fp32 accumulate + fp32 h output. */
__global__ __launch_bounds__(192, 4) void kconv(const float* __restrict__ x, float* __restrict__ ws) {
    __shared__ __bf16 xt[ZPL*YROWP*XTS_E];             /* 14*23*30*2 = 19320 B */
    int tid = threadIdx.x;
    int bx = blockIdx.x;                               /* 36 = 6z * 3y * 2x */
    int zt = bx / 6;
    int rt = bx % 6; int yt = rt >> 1; int xti = rt & 1;
    int c = blockIdx.y, b = blockIdx.z;
    int z0 = zt*ZSPAN, y0 = yt*YSPAN, x0 = xti*XSPAN;

    const float* xsrc = x + ((size_t)(b*DIM + c))*SP3;
    for (int i = tid; i < ZPL*YROWS*XTS_E; i += 192) { /* 9240 elems */
        int iz = i / (YROWS*XTS_E); int r = i % (YROWS*XTS_E);
        int iy = r / XTS_E; int ix = r % XTS_E;
        int gz = z0 - 3 + iz, gy = y0 - 3 + iy, gx = x0 + ix - 3;
        float v = 0.f;
        if ((unsigned)gz < 48u && (unsigned)gy < 48u && (unsigned)gx < 48u)
            v = xsrc[(gz*SPD + gy)*SPD + gx];
        xt[(iz*YROWP + iy)*XTS_E + ix] = (__bf16)v;
    }
    __syncthreads();

    int tz = tid / 24; int rem = tid % 24; int ty = rem / 3; int tx = rem % 3;
    int xb = tx*8;
    float acc[YB][8];
    #pragma unroll
    for (int yl = 0; yl < YB; ++yl)
        #pragma unroll
        for (int j = 0; j < 8; ++j) acc[yl][j] = 0.f;

    const float* wsrc = ws + WS_WDW + ((size_t)(b*DIM + c))*343;

    #pragma unroll 1
    for (int dz = 0; dz < 7; ++dz) {
        /* this dz's 49 weights: uniform global loads (L2-hit, s_load broadcast) */
        float wv[7][7];
        const float* wp = wsrc + dz*49;
        #pragma unroll
        for (int dy = 0; dy < 7; ++dy)
            #pragma unroll
            for (int dx = 0; dx < 7; ++dx)
                wv[dy][dx] = wp[dy*7 + dx];

        const int zr = (tz + dz)*YROWP + ty*YB;
        #pragma unroll
        for (int r = 0; r < YB + 6; ++r) {
            /* 14-elem bf16 window = 7 dwords; base elem even -> 4B aligned.
               dword stride 15 (odd) -> full 32-bank spread; alignment>4B
               unprovable -> compiler emits b32/ds_read2_b32 (no b128). */
            const uint32_t* rowp = (const uint32_t*)&xt[(zr + r)*XTS_E + xb];
            uint32_t dw[7];
            #pragma unroll
            for (int k = 0; k < 7; ++k) dw[k] = rowp[k];
            float rr[14];
            #pragma unroll
            for (int k = 0; k < 7; ++k) {
                rr[2*k]   = __uint_as_float(dw[k] << 16);
                rr[2*k+1] = __uint_as_float(dw[k] & 0xffff0000u);
            }
            #pragma unroll
            for (int yl = 0; yl < YB; ++yl) {
                const int dy = r - yl;
                if (dy >= 0 && dy < 7) {
                    #pragma unroll
                    for (int dx = 0; dx < 7; ++dx)
                        #pragma unroll
                        for (int j = 0; j < 8; ++j)
                            acc[yl][j] += wv[dy][dx]*rr[dx+j];
                }
            }
        }
    }

    float bias = ws[WS_BDW + b*DIM + c];
    #pragma unroll
    for (int yl = 0; yl < YB; ++yl) {
        float* hdst = ws + WS_H + ((size_t)(b*DIM + c))*SP3
                    + (((z0+tz)*SPD + (y0 + ty*YB + yl))*SPD + (x0 + xb));
        #pragma unroll
        for (int j = 0; j < 8; ++j) hdst[j] = acc[yl][j] + bias;
    }
}

/* ---------- kernel 4: LN + pw1 + GELU + pw2 + residual, MFMA version ---- */
__global__ __launch_bounds__(256) void kpw(const float* __restrict__ x,
                                           const float* __restrict__ lnw, const float* __restrict__ lnb,
                                           const float* __restrict__ gamma,
                                           float* __restrict__ out, const float* __restrict__ ws) {
    __shared__ __align__(16) __bf16 Hn[64][104];   /* 13312 B */
    __shared__ __align__(16) __bf16 G[64][392];    /* 50176 B */
    __shared__ float2 redbuf[256];                 /*  2048 B */

    const int tid  = threadIdx.x;
    const int lane = tid & 63;
    const int w    = tid >> 6;          /* wave id: Phase-A channel quarter, GEMM N-tile */
    const int b    = blockIdx.y;
    const int sp0  = blockIdx.x * 64;

    /* ---- Phase A: load h, LayerNorm, write bf16 Hn ---- */
    {
        const float* hp = ws + WS_H + (size_t)b*DIM*SP3 + (size_t)(w*24)*SP3 + sp0 + lane;
        float hv[24]; float s = 0.f, q = 0.f;
        #pragma unroll
        for (int i = 0; i < 24; ++i) {
            float v = hp[(size_t)i*SP3];
            hv[i] = v; s += v; q += v*v;
        }
        redbuf[w*64 + lane] = make_float2(s, q);
        __syncthreads();
        float2 r0 = redbuf[lane], r1 = redbuf[64+lane], r2 = redbuf[128+lane], r3 = redbuf[192+lane];
        float st = (r0.x+r1.x) + (r2.x+r3.x);
        float qt = (r0.y+r1.y) + (r2.y+r3.y);
        float mean = st * (1.f/96.f);
        float var  = qt * (1.f/96.f) - mean*mean;
        float rstd = rsqrtf(fmaxf(var, 0.f) + EPSV);
        #pragma unroll
        for (int i = 0; i < 24; ++i) {
            float nv = (hv[i] - mean)*rstd*lnw[w*24+i] + lnb[w*24+i];
            Hn[lane][w*24 + i] = (__bf16)nv;
        }
    }
    __syncthreads();

    const __bf16* W1b = (const __bf16*)(ws + WS_W1)  + (size_t)b*C4*DIM;
    const __bf16* W2b = (const __bf16*)(ws + WS_W2T) + (size_t)b*DIM*C4;
    const float*  b1  = ws + WS_B1 + b*C4;
    const float*  b2  = ws + WS_B2 + b*DIM;

    const int l16  = lane & 15;
    const int quad = lane >> 4;

    /* ---- GEMM1: G[n][o] = gelu(W1 @ Hn + b1), N-tile w ---- */
    {
        const __bf16* bp = &Hn[w*16 + l16][quad*8];
        bf16x8 Bf0 = *(const bf16x8*)(bp);
        bf16x8 Bf1 = *(const bf16x8*)(bp + 32);
        bf16x8 Bf2 = *(const bf16x8*)(bp + 64);

        const __bf16* Arow = W1b + (size_t)l16*DIM + quad*8;
        #pragma unroll 1
        for (int mt = 0; mt < 24; ++mt) {
            const __bf16* ap = Arow + (size_t)mt*16*DIM;
            bf16x8 a0 = *(const bf16x8*)(ap);
            bf16x8 a1 = *(const bf16x8*)(ap + 32);
            bf16x8 a2 = *(const bf16x8*)(ap + 64);
            f32x4 acc = {0.f, 0.f, 0.f, 0.f};
            acc = __builtin_amdgcn_mfma_f32_16x16x32_bf16(a0, Bf0, acc, 0, 0, 0);
            acc = __builtin_amdgcn_mfma_f32_16x16x32_bf16(a1, Bf1, acc, 0, 0, 0);
            acc = __builtin_amdgcn_mfma_f32_16x16x32_bf16(a2, Bf2, acc, 0, 0, 0);
            int obase = mt*16 + quad*4;
            bf16x4 gv;
            #pragma unroll
            for (int r = 0; r < 4; ++r) {
                float t = acc[r] + b1[obase + r];
                float g = 0.5f*t*(1.f + erff(t*0.70710678f));
                gv[r] = (__bf16)g;
            }
            *(bf16x4*)&G[w*16 + l16][obase] = gv;
        }
    }
    __syncthreads();   /* enforce G write->read ordering */

    /* ---- GEMM2: out = x + gamma*(W2 @ G + b2), N-tile w ---- */
    {
        bf16x8 Bg[12];
        const __bf16* gbp = &G[w*16 + l16][quad*8];
        #pragma unroll
        for (int ks = 0; ks < 12; ++ks)
            Bg[ks] = *(const bf16x8*)(gbp + ks*32);

        const __bf16* A2row = W2b + (size_t)l16*C4 + quad*8;
        const int j = w*16 + l16;
        const size_t base = (size_t)b*DIM*SP3 + sp0 + j;
        #pragma unroll 1
        for (int mt = 0; mt < 6; ++mt) {
            const __bf16* ap = A2row + (size_t)mt*16*C4;
            f32x4 acc = {0.f, 0.f, 0.f, 0.f};
            #pragma unroll
            for (int ks = 0; ks < 12; ++ks) {
                bf16x8 a = *(const bf16x8*)(ap + ks*32);
                acc = __builtin_amdgcn_mfma_f32_16x16x32_bf16(a, Bg[ks], acc, 0, 0, 0);
            }
            int obase = mt*16 + quad*4;
            #pragma unroll
            for (int r = 0; r < 4; ++r) {
                int o = obase + r;
                size_t idx = base + (size_t)o*SP3;
                float y = acc[r] + b2[o];
                out[idx] = x[idx] + gamma[o]*y;
            }
        }
    }
}

extern "C" void kernel_launch(void* const* d_in, const int* in_sizes, int n_in,
                              void* d_out, int out_size, void* d_ws, size_t ws_size,
                              hipStream_t stream) {
    const float* x      = (const float*)d_in[0];
    const float* s      = (const float*)d_in[1];
    const float* lnw    = (const float*)d_in[2];
    const float* lnb    = (const float*)d_in[3];
    const float* gamma  = (const float*)d_in[4];
    const float* dwfw   = (const float*)d_in[5];
    const float* dwfb   = (const float*)d_in[6];
    const float* dwbank = (const float*)d_in[7];
    const float* dwbb   = (const float*)d_in[8];
    const float* p1fw   = (const float*)d_in[9];
    const float* p1fb   = (const float*)d_in[10];
    const float* p1bank = (const float*)d_in[11];
    const float* p1bb   = (const float*)d_in[12];
    const float* p2fw   = (const float*)d_in[13];
    const float* p2fb   = (const float*)d_in[14];
    const float* p2bank = (const float*)d_in[15];
    const float* p2bb   = (const float*)d_in[16];
    float* ws  = (float*)d_ws;
    float* out = (float*)d_out;

    kz<<<1, 64, 0, stream>>>(s, dwfw, dwfb, p1fw, p1fb, p2fw, p2fb, ws);
    const int totW = BB*DIM*343 + BB*DIM + BB*C4*DIM + BB*C4 + BB*C4*DIM + BB*DIM;
    kw<<<(totW + 255)/256, 256, 0, stream>>>(dwbank, dwbb, p1bank, p1bb, p2bank, p2bb, ws);
    kconv<<<dim3(36, DIM, BB), 192, 0, stream>>>(x, ws);
    kpw<<<dim3(SP3/64, BB), 256, 0, stream>>>(x, lnw, lnb, gamma, out, ws);
}

// Round 6
// 625.504 us; speedup vs baseline: 1.8822x; 1.0902x over previous
//
#include <hip/hip_runtime.h>
#include <math.h>

#define DIM   96
#define C4    384
#define STYLE 128
#define LAT   8
#define KK    7
#define BB    2
#define SPD   48
#define SP3   (SPD*SPD*SPD)   /* 110592 */
#define EPSV  1e-6f

/* ---- kconv tile geometry (R11, kept verbatim: passed @ 3.05e-5) ---- */
#define XTS_E 30              /* bf16 elems per row slot (dword stride 15 odd) */
#define YB    2
#define YSPAN 16              /* 8 ty * YB */
#define ZSPAN 8
#define XSPAN 24              /* 3 tx * 8 */
#define YROWS 22              /* YSPAN+6 staged rows */
#define YROWP 23              /* row-slot stride per z-plane */
#define ZPL   14              /* ZSPAN+6 planes */

/* workspace layout in floats */
#define WS_Z    0                               /* 48: [which3][b2][l8] */
#define WS_WDW  64                              /* 2*96*343 = 65856, [b][c][k] fp32 */
#define WS_BDW  (WS_WDW + BB*DIM*343)           /* 192, [b][c] fp32 */
#define WS_W1   (WS_BDW + BB*DIM)               /* region holds W1b bf16 [b][384][96] */
#define WS_B1   (WS_W1 + BB*C4*DIM)             /* 768 fp32, [b][o4] */
#define WS_W2T  (WS_B1 + BB*C4)                 /* region holds W2b bf16 [b][96][384] */
#define WS_B2   (WS_W2T + BB*C4*DIM)            /* 192 fp32, [b][o] */
#define WS_H    (WS_B2 + BB*DIM)                /* 2*96*110592 fp32, [b][c][sp] */

typedef __attribute__((ext_vector_type(8))) __bf16 bf16x8;
typedef __attribute__((ext_vector_type(4))) __bf16 bf16x4;
typedef __attribute__((ext_vector_type(4))) float  f32x4;

/* ---------- kernel 1: style -> latent z for the three hyper nets ---------- */
__global__ __launch_bounds__(64) void kz(const float* __restrict__ s,
                                         const float* __restrict__ dwfw, const float* __restrict__ dwfb,
                                         const float* __restrict__ p1fw, const float* __restrict__ p1fb,
                                         const float* __restrict__ p2fw, const float* __restrict__ p2fb,
                                         float* __restrict__ ws) {
    int t = threadIdx.x;
    if (t >= 48) return;
    int which = t >> 4;      /* 0=dw, 1=pw1, 2=pw2 */
    int b = (t >> 3) & 1;
    int l = t & 7;
    const float* fw = (which == 0) ? dwfw : (which == 1) ? p1fw : p2fw;
    const float* fb = (which == 0) ? dwfb : (which == 1) ? p1fb : p2fb;
    float acc = fb[l];
    for (int k = 0; k < STYLE; ++k) acc += s[b*STYLE + k] * fw[l*STYLE + k];
    ws[WS_Z + which*16 + b*8 + l] = acc;
}

/* ---------- kernel 2: latent z -> per-batch conv weights/biases ---------- */
__global__ __launch_bounds__(256) void kw(const float* __restrict__ dwb,  const float* __restrict__ dwbb,
                                          const float* __restrict__ p1b,  const float* __restrict__ p1bb,
                                          const float* __restrict__ p2b,  const float* __restrict__ p2bb,
                                          float* __restrict__ ws) {
    const int n0 = BB*DIM*343;          /* w_dw  */
    const int n1 = n0 + BB*DIM;         /* b_dw  */
    const int n2 = n1 + BB*C4*DIM;      /* w1    */
    const int n3 = n2 + BB*C4;          /* b1    */
    const int n4 = n3 + BB*C4*DIM;      /* w2    */
    const int n5 = n4 + BB*DIM;         /* b2    */
    int i = blockIdx.x * blockDim.x + threadIdx.x;
    if (i >= n5) return;
    const float* zdw = ws + WS_Z;
    const float* z1  = ws + WS_Z + 16;
    const float* z2  = ws + WS_Z + 32;
    if (i < n0) {
        int b = i / (DIM*343); int r = i % (DIM*343); int c = r / 343; int k = r % 343;
        const float* bank = dwb + ((size_t)(c*343 + k))*LAT;
        const float* z = zdw + b*8;
        float a = 0.f;
        #pragma unroll
        for (int l = 0; l < LAT; ++l) a += bank[l]*z[l];
        ws[WS_WDW + i] = a;
    } else if (i < n1) {
        int j = i - n0; int b = j / DIM; int c = j % DIM;
        const float* z = zdw + b*8;
        float a = 0.f;
        #pragma unroll
        for (int l = 0; l < LAT; ++l) a += dwbb[c*LAT + l]*z[l];
        ws[WS_BDW + j] = a;
    } else if (i < n2) {
        int j = i - n1; int b = j / (C4*DIM); int r = j % (C4*DIM); int o = r / DIM; int c = r % DIM;
        const float* z = z1 + b*8;
        const float* bank = p1b + ((size_t)(o*DIM + c))*LAT;
        float a = 0.f;
        #pragma unroll
        for (int l = 0; l < LAT; ++l) a += bank[l]*z[l];
        ((__bf16*)(ws + WS_W1))[j] = (__bf16)a;          /* [b][o][c] */
    } else if (i < n3) {
        int j = i - n2; int b = j / C4; int o = j % C4;
        const float* z = z1 + b*8;
        float a = 0.f;
        #pragma unroll
        for (int l = 0; l < LAT; ++l) a += p1bb[o*LAT + l]*z[l];
        ws[WS_B1 + j] = a;
    } else if (i < n4) {
        int j = i - n3; int b = j / (C4*DIM); int r = j % (C4*DIM); int o = r / C4; int c4 = r % C4;
        const float* z = z2 + b*8;
        const float* bank = p2b + ((size_t)(o*C4 + c4))*LAT;
        float a = 0.f;
        #pragma unroll
        for (int l = 0; l < LAT; ++l) a += bank[l]*z[l];
        ((__bf16*)(ws + WS_W2T))[j] = (__bf16)a;         /* [b][o][c4] */
    } else {
        int j = i - n4; int b = j / DIM; int o = j % DIM;
        const float* z = z2 + b*8;
        float a = 0.f;
        #pragma unroll
        for (int l = 0; l < LAT; ++l) a += p2bb[o*LAT + l]*z[l];
        ws[WS_B2 + j] = a;
    }
}

/* ---------- kernel 3: depthwise 7x7x7 conv (+bias) -> h in ws ----------
   R11 (verified): bf16 LDS x-tile (19320 B), 8z x 16y x 24x, YB=2 ring,
   odd dword strides, dword reads + 2-VALU unpack, weights uniform from
   global, fp32 accumulate + fp32 h output. */
__global__ __launch_bounds__(192, 4) void kconv(const float* __restrict__ x, float* __restrict__ ws) {
    __shared__ __bf16 xt[ZPL*YROWP*XTS_E];             /* 14*23*30*2 = 19320 B */
    int tid = threadIdx.x;
    int bx = blockIdx.x;                               /* 36 = 6z * 3y * 2x */
    int zt = bx / 6;
    int rt = bx % 6; int yt = rt >> 1; int xti = rt & 1;
    int c = blockIdx.y, b = blockIdx.z;
    int z0 = zt*ZSPAN, y0 = yt*YSPAN, x0 = xti*XSPAN;

    const float* xsrc = x + ((size_t)(b*DIM + c))*SP3;
    for (int i = tid; i < ZPL*YROWS*XTS_E; i += 192) { /* 9240 elems */
        int iz = i / (YROWS*XTS_E); int r = i % (YROWS*XTS_E);
        int iy = r / XTS_E; int ix = r % XTS_E;
        int gz = z0 - 3 + iz, gy = y0 - 3 + iy, gx = x0 + ix - 3;
        float v = 0.f;
        if ((unsigned)gz < 48u && (unsigned)gy < 48u && (unsigned)gx < 48u)
            v = xsrc[(gz*SPD + gy)*SPD + gx];
        xt[(iz*YROWP + iy)*XTS_E + ix] = (__bf16)v;
    }
    __syncthreads();

    int tz = tid / 24; int rem = tid % 24; int ty = rem / 3; int tx = rem % 3;
    int xb = tx*8;
    float acc[YB][8];
    #pragma unroll
    for (int yl = 0; yl < YB; ++yl)
        #pragma unroll
        for (int j = 0; j < 8; ++j) acc[yl][j] = 0.f;

    const float* wsrc = ws + WS_WDW + ((size_t)(b*DIM + c))*343;

    #pragma unroll 1
    for (int dz = 0; dz < 7; ++dz) {
        float wv[7][7];
        const float* wp = wsrc + dz*49;
        #pragma unroll
        for (int dy = 0; dy < 7; ++dy)
            #pragma unroll
            for (int dx = 0; dx < 7; ++dx)
                wv[dy][dx] = wp[dy*7 + dx];

        const int zr = (tz + dz)*YROWP + ty*YB;
        #pragma unroll
        for (int r = 0; r < YB + 6; ++r) {
            const uint32_t* rowp = (const uint32_t*)&xt[(zr + r)*XTS_E + xb];
            uint32_t dw[7];
            #pragma unroll
            for (int k = 0; k < 7; ++k) dw[k] = rowp[k];
            float rr[14];
            #pragma unroll
            for (int k = 0; k < 7; ++k) {
                rr[2*k]   = __uint_as_float(dw[k] << 16);
                rr[2*k+1] = __uint_as_float(dw[k] & 0xffff0000u);
            }
            #pragma unroll
            for (int yl = 0; yl < YB; ++yl) {
                const int dy = r - yl;
                if (dy >= 0 && dy < 7) {
                    #pragma unroll
                    for (int dx = 0; dx < 7; ++dx)
                        #pragma unroll
                        for (int j = 0; j < 8; ++j)
                            acc[yl][j] += wv[dy][dx]*rr[dx+j];
                }
            }
        }
    }

    float bias = ws[WS_BDW + b*DIM + c];
    #pragma unroll
    for (int yl = 0; yl < YB; ++yl) {
        float* hdst = ws + WS_H + ((size_t)(b*DIM + c))*SP3
                    + (((z0+tz)*SPD + (y0 + ty*YB + yl))*SPD + (x0 + xb));
        #pragma unroll
        for (int j = 0; j < 8; ++j) hdst[j] = acc[yl][j] + bias;
    }
}

/* ---------- kernel 4: LN + pw1 + GELU + pw2 + residual ----------
   R12: chunked-G. R11 post-mortem: kpw 305 us, MfmaUtil 4.3%, VALUBusy
   17%, Occ 21.9% (65536 B LDS -> 2 blocks/CU under the ~110-120 KB
   effective pool seen on kconv R9/R10) -> pure latency-bound. Fix: G
   never needs to exist in full — interleave GEMM1/GEMM2 in 4 chunks of
   96 o-values reusing one Gq[64][104] buffer. GEMM2 accumulators
   acc2[6][4] live in registers across chunks (mt2 loop fully unrolled ->
   static indexing, no scratch). LDS 65536 -> 28672 B -> 3-4 blocks/CU.
   All fragment layouts / load patterns byte-identical to the verified
   R11 kernel; only iteration order + 8 barriers changed. */
__global__ __launch_bounds__(256) void kpw(const float* __restrict__ x,
                                           const float* __restrict__ lnw, const float* __restrict__ lnb,
                                           const float* __restrict__ gamma,
                                           float* __restrict__ out, const float* __restrict__ ws) {
    __shared__ __align__(16) __bf16 Hn[64][104];   /* 13312 B */
    __shared__ __align__(16) __bf16 Gq[64][104];   /* 13312 B (96 cols used) */
    __shared__ float2 redbuf[256];                 /*  2048 B -> total 28672 */

    const int tid  = threadIdx.x;
    const int lane = tid & 63;
    const int w    = tid >> 6;          /* wave id: Phase-A channel quarter, GEMM N-tile */
    const int b    = blockIdx.y;
    const int sp0  = blockIdx.x * 64;

    /* ---- Phase A: load h, LayerNorm, write bf16 Hn ---- */
    {
        const float* hp = ws + WS_H + (size_t)b*DIM*SP3 + (size_t)(w*24)*SP3 + sp0 + lane;
        float hv[24]; float s = 0.f, q = 0.f;
        #pragma unroll
        for (int i = 0; i < 24; ++i) {
            float v = hp[(size_t)i*SP3];
            hv[i] = v; s += v; q += v*v;
        }
        redbuf[w*64 + lane] = make_float2(s, q);
        __syncthreads();
        float2 r0 = redbuf[lane], r1 = redbuf[64+lane], r2 = redbuf[128+lane], r3 = redbuf[192+lane];
        float st = (r0.x+r1.x) + (r2.x+r3.x);
        float qt = (r0.y+r1.y) + (r2.y+r3.y);
        float mean = st * (1.f/96.f);
        float var  = qt * (1.f/96.f) - mean*mean;
        float rstd = rsqrtf(fmaxf(var, 0.f) + EPSV);
        #pragma unroll
        for (int i = 0; i < 24; ++i) {
            float nv = (hv[i] - mean)*rstd*lnw[w*24+i] + lnb[w*24+i];
            Hn[lane][w*24 + i] = (__bf16)nv;
        }
    }
    __syncthreads();

    const __bf16* W1b = (const __bf16*)(ws + WS_W1)  + (size_t)b*C4*DIM;
    const __bf16* W2b = (const __bf16*)(ws + WS_W2T) + (size_t)b*DIM*C4;
    const float*  b1  = ws + WS_B1 + b*C4;
    const float*  b2  = ws + WS_B2 + b*DIM;

    const int l16  = lane & 15;
    const int quad = lane >> 4;

    /* Hn B-fragments for this wave's sp N-tile (reused by all 4 chunks) */
    const __bf16* bp = &Hn[w*16 + l16][quad*8];
    bf16x8 Bf0 = *(const bf16x8*)(bp);
    bf16x8 Bf1 = *(const bf16x8*)(bp + 32);
    bf16x8 Bf2 = *(const bf16x8*)(bp + 64);

    /* GEMM2 accumulators: 6 o-tiles x 4 rows, static-indexed throughout */
    float acc2[6][4];
    #pragma unroll
    for (int m = 0; m < 6; ++m)
        #pragma unroll
        for (int r = 0; r < 4; ++r) acc2[m][r] = 0.f;

    #pragma unroll 1
    for (int q = 0; q < 4; ++q) {
        /* ---- GEMM1 chunk: o = q*96 .. q*96+95 -> gelu -> Gq ---- */
        #pragma unroll 1
        for (int mtl = 0; mtl < 6; ++mtl) {
            const __bf16* ap = W1b + (size_t)((q*6 + mtl)*16 + l16)*DIM + quad*8;
            bf16x8 a0 = *(const bf16x8*)(ap);
            bf16x8 a1 = *(const bf16x8*)(ap + 32);
            bf16x8 a2 = *(const bf16x8*)(ap + 64);
            f32x4 acc = {0.f, 0.f, 0.f, 0.f};
            acc = __builtin_amdgcn_mfma_f32_16x16x32_bf16(a0, Bf0, acc, 0, 0, 0);
            acc = __builtin_amdgcn_mfma_f32_16x16x32_bf16(a1, Bf1, acc, 0, 0, 0);
            acc = __builtin_amdgcn_mfma_f32_16x16x32_bf16(a2, Bf2, acc, 0, 0, 0);
            int og = (q*6 + mtl)*16 + quad*4;   /* global o for bias */
            int ol = mtl*16 + quad*4;           /* local col in Gq */
            bf16x4 gv;
            #pragma unroll
            for (int r = 0; r < 4; ++r) {
                float t = acc[r] + b1[og + r];
                float g = 0.5f*t*(1.f + erff(t*0.70710678f));
                gv[r] = (__bf16)g;
            }
            *(bf16x4*)&Gq[w*16 + l16][ol] = gv;
        }
        __syncthreads();   /* Gq write -> read */

        /* ---- GEMM2 partial: k = q*96 + ksl*32, accumulate acc2 ---- */
        #pragma unroll 1
        for (int ksl = 0; ksl < 3; ++ksl) {
            bf16x8 Bg = *(const bf16x8*)&Gq[w*16 + l16][ksl*32 + quad*8];
            const int kbase = q*96 + ksl*32 + quad*8;
            #pragma unroll
            for (int mt2 = 0; mt2 < 6; ++mt2) {
                const __bf16* ap2 = W2b + (size_t)(mt2*16 + l16)*C4 + kbase;
                bf16x8 a = *(const bf16x8*)(ap2);
                f32x4 c = {acc2[mt2][0], acc2[mt2][1], acc2[mt2][2], acc2[mt2][3]};
                c = __builtin_amdgcn_mfma_f32_16x16x32_bf16(a, Bg, c, 0, 0, 0);
                acc2[mt2][0] = c[0]; acc2[mt2][1] = c[1];
                acc2[mt2][2] = c[2]; acc2[mt2][3] = c[3];
            }
        }
        __syncthreads();   /* Gq read done before next chunk overwrites */
    }

    /* ---- epilogue: out = x + gamma*(acc2 + b2) ---- */
    const int j = w*16 + l16;
    const size_t base = (size_t)b*DIM*SP3 + sp0 + j;
    #pragma unroll
    for (int mt2 = 0; mt2 < 6; ++mt2) {
        int obase = mt2*16 + quad*4;
        #pragma unroll
        for (int r = 0; r < 4; ++r) {
            int o = obase + r;
            size_t idx = base + (size_t)o*SP3;
            float y = acc2[mt2][r] + b2[o];
            out[idx] = x[idx] + gamma[o]*y;
        }
    }
}

extern "C" void kernel_launch(void* const* d_in, const int* in_sizes, int n_in,
                              void* d_out, int out_size, void* d_ws, size_t ws_size,
                              hipStream_t stream) {
    const float* x      = (const float*)d_in[0];
    const float* s      = (const float*)d_in[1];
    const float* lnw    = (const float*)d_in[2];
    const float* lnb    = (const float*)d_in[3];
    const float* gamma  = (const float*)d_in[4];
    const float* dwfw   = (const float*)d_in[5];
    const float* dwfb   = (const float*)d_in[6];
    const float* dwbank = (const float*)d_in[7];
    const float* dwbb   = (const float*)d_in[8];
    const float* p1fw   = (const float*)d_in[9];
    const float* p1fb   = (const float*)d_in[10];
    const float* p1bank = (const float*)d_in[11];
    const float* p1bb   = (const float*)d_in[12];
    const float* p2fw   = (const float*)d_in[13];
    const float* p2fb   = (const float*)d_in[14];
    const float* p2bank = (const float*)d_in[15];
    const float* p2bb   = (const float*)d_in[16];
    float* ws  = (float*)d_ws;
    float* out = (float*)d_out;

    kz<<<1, 64, 0, stream>>>(s, dwfw, dwfb, p1fw, p1fb, p2fw, p2fb, ws);
    const int totW = BB*DIM*343 + BB*DIM + BB*C4*DIM + BB*C4 + BB*C4*DIM + BB*DIM;
    kw<<<(totW + 255)/256, 256, 0, stream>>>(dwbank, dwbb, p1bank, p1bb, p2bank, p2bb, ws);
    kconv<<<dim3(36, DIM, BB), 192, 0, stream>>>(x, ws);
    kpw<<<dim3(SP3/64, BB), 256, 0, stream>>>(x, lnw, lnb, gamma, out, ws);
}